// Round 2
// baseline (338.151 us; speedup 1.0000x reference)
//
#include <hip/hip_runtime.h>

// Local variance over a 5x5 sliding window, reflect padding.
// Pure-register separable stencil: NO LDS, NO barriers.
//
// Thread tile: 4 (W) x 16 (H) outputs. Block: 64 threads across W (256 cols),
// 4 thread-rows of 16 (64 rows). Grid: (W/256, H/64, B*C) = (4, 16, 48).
//
// Per input row (20 rows = 16 + 4 halo): 3 aligned float4 loads give cols
// c0-4 .. c0+7; the needed window is c0-2 .. c0+5. Horizontal 5-sums of x
// and x^2 via sliding adds; vertical 5-window via a register ring buffer
// (fully unrolled -> pure registers, ring depth 5 regardless of tile height).
//
// vs previous 4x8 version: vertical halo amplification 1.5x -> 1.25x at
// thread level (1.125x -> 1.06x at block/HBM level), load-instructions per
// output 1.125 -> 0.94, row address/reflect math amortized over 2x outputs.
// Output stores are nontemporal (via clang ext-vector type — HIP float4 is
// rejected by the builtin): the result is never re-read, so keep L2/L3
// lines for input halo reuse instead.
//
// Reflect (jnp "reflect", no edge repeat): rows are wave-uniform index math.
// Columns: clamp the two halo loads to the row, then:
//   left edge  (c0==0):    x2 needs col -2 -> col 2 == clamped v0.z (auto);
//                          x3 needs col -1 -> col 1  => x3 = x5
//   right edge (c0==W-4):  x8 needs col W  -> col W-2 => x8 = x6;
//                          x9 needs col W+1 -> col W-3 == clamped v2.y (auto)

constexpr int NT = 256;

typedef float v4f __attribute__((ext_vector_type(4)));

__global__ __launch_bounds__(NT, 4)
void lvar5x5_reg_kernel(const float* __restrict__ in, float* __restrict__ out,
                        int H, int W) {
    const int tx = threadIdx.x & 63;     // column group within block
    const int ty = threadIdx.x >> 6;     // thread-row (wave-uniform)
    const int c0 = blockIdx.x * 256 + tx * 4;   // first output col
    const int r0 = blockIdx.y * 64 + ty * 16;   // first output row
    const size_t plane = (size_t)H * W;
    const float* __restrict__ img = in + (size_t)blockIdx.z * plane;
    float* __restrict__ o = out + (size_t)blockIdx.z * plane;

    const bool cL = (c0 == 0);
    const bool cR = (c0 == W - 4);
    const int a0 = cL ? 0 : c0 - 4;      // clamped left halo load col
    const int a2 = cR ? c0 : c0 + 4;     // clamped right halo load col

    float rh[5][4];                      // ring: horizontal sums of x
    float rq[5][4];                      // ring: horizontal sums of x^2
    float sh0 = 0.f, sh1 = 0.f, sh2 = 0.f, sh3 = 0.f;  // vertical running sums
    float sq0 = 0.f, sq1 = 0.f, sq2 = 0.f, sq3 = 0.f;

    const float inv = 1.0f / 25.0f;

#pragma unroll
    for (int i = 0; i < 20; ++i) {
        int gy = r0 - 2 + i;
        gy = (gy < 0) ? -gy : ((gy >= H) ? (2 * H - 2 - gy) : gy);
        const float* __restrict__ row = img + (size_t)gy * W;

        const float4 v0 = *reinterpret_cast<const float4*>(row + a0);
        const float4 v1 = *reinterpret_cast<const float4*>(row + c0);
        const float4 v2 = *reinterpret_cast<const float4*>(row + a2);

        const float x2 = v0.z;                 // col c0-2 (auto-correct at left edge)
        float       x3 = v0.w;                 // col c0-1
        const float x4 = v1.x, x5 = v1.y, x6 = v1.z, x7 = v1.w;
        float       x8 = v2.x;                 // col c0+4
        const float x9 = v2.y;                 // col c0+5 (auto-correct at right edge)
        if (cL) x3 = x5;                       // reflect col -1 -> col 1
        if (cR) x8 = x6;                       // reflect col W  -> col W-2

        // horizontal sliding 5-sums
        const float h0 = x2 + x3 + x4 + x5 + x6;
        const float h1 = h0 - x2 + x7;
        const float h2 = h1 - x3 + x8;
        const float h3 = h2 - x4 + x9;

        const float y2 = x2 * x2, y3 = x3 * x3, y4 = x4 * x4, y5 = x5 * x5;
        const float y6 = x6 * x6, y7 = x7 * x7, y8 = x8 * x8, y9 = x9 * x9;
        const float q0 = y2 + y3 + y4 + y5 + y6;
        const float q1 = q0 - y2 + y7;
        const float q2 = q1 - y3 + y8;
        const float q3 = q2 - y4 + y9;

        const int s = i % 5;                   // constant after unroll
        if (i >= 5) {
            sh0 -= rh[s][0]; sh1 -= rh[s][1]; sh2 -= rh[s][2]; sh3 -= rh[s][3];
            sq0 -= rq[s][0]; sq1 -= rq[s][1]; sq2 -= rq[s][2]; sq3 -= rq[s][3];
        }
        rh[s][0] = h0; rh[s][1] = h1; rh[s][2] = h2; rh[s][3] = h3;
        rq[s][0] = q0; rq[s][1] = q1; rq[s][2] = q2; rq[s][3] = q3;
        sh0 += h0; sh1 += h1; sh2 += h2; sh3 += h3;
        sq0 += q0; sq1 += q1; sq2 += q2; sq3 += q3;

        if (i >= 4) {
            v4f res;
            float m;
            m = sh0 * inv; res.x = fmaf(-m, m, sq0 * inv);
            m = sh1 * inv; res.y = fmaf(-m, m, sq1 * inv);
            m = sh2 * inv; res.z = fmaf(-m, m, sq2 * inv);
            m = sh3 * inv; res.w = fmaf(-m, m, sq3 * inv);
            __builtin_nontemporal_store(
                res, reinterpret_cast<v4f*>(o + (size_t)(r0 + i - 4) * W + c0));
        }
    }
}

extern "C" void kernel_launch(void* const* d_in, const int* in_sizes, int n_in,
                              void* d_out, int out_size, void* d_ws, size_t ws_size,
                              hipStream_t stream) {
    const float* image = (const float*)d_in[0];
    float* out = (float*)d_out;

    const int H = 1024, W = 1024;
    const int BC = out_size / (H * W);     // 48

    dim3 grid(W / 256, H / 64, BC);        // (4, 16, 48) = 3072 blocks
    dim3 block(NT);
    lvar5x5_reg_kernel<<<grid, block, 0, stream>>>(image, out, H, W);
}